// Round 13
// baseline (175.350 us; speedup 1.0000x reference)
//
#include <hip/hip_runtime.h>

// B=2, L=16384, Nv=8, C=196, H=4, d=49.
// Factored algorithm (per position t):
//   qln = LN(query);  qk[h,c] = sum_d qln[h*49+d]*Wk[h*49+d,c]          (GEMM1, MFMA)
//   score[h,n] = (sum_c qk[h,c]*ctx[n,c] + qln_h.bk_h)/7 ; p = softmax  (VALU)
//   cbar[h,c] = sum_n p[h,n]*ctx[n,c]                                   (VALU)
//   out[o] = sum_c cbar[h(o),c]*Wv[o,c] + bv[o]                         (GEMM2, MFMA)
// === ROUND-3 KERNEL VERBATIM (best measured margin: absmax 0.0181, 176.5us).
// R12 proved absmax is environment-dependent (identical source: 0.0547->0.0937),
// so we lock the family with 4x threshold margin. Single code path, no ws use.
namespace {
constexpr int kL = 16384;
constexpr int kTile = 16;              // positions per WG
constexpr float kEps = 1e-5f;
constexpr float kScale = 1.0f / 7.0f;  // 1/sqrt(49)

typedef short bf16x8 __attribute__((ext_vector_type(8)));  // 8 bf16 (4 VGPR)
typedef float f32x4 __attribute__((ext_vector_type(4)));

__device__ __forceinline__ unsigned short f2bf(float x) {  // RNE f32->bf16
  unsigned u = __builtin_bit_cast(unsigned, x);
  u = u + 0x7fffu + ((u >> 16) & 1u);
  return (unsigned short)(u >> 16);
}
__device__ __forceinline__ float bf2f(unsigned short s) {
  return __builtin_bit_cast(float, (unsigned)s << 16);
}

// LDS geometry (elements are bf16 unless noted)
constexpr int QLN_ROW = 296;   // 4 h-blocks of 72 (k=0..63 used, 49..63 zero) ; 592B row
constexpr int QK_ROW  = 904;   // 4 h-blocks of 224 (c pad zero 196..223)      ; 1808B row
constexpr int PNL_ELEMS = 14336;  // weight panel, fragment-native order

__global__ __launch_bounds__(256, 2)
void fused_triplane(const float* __restrict__ query,
                    const float* __restrict__ context,
                    const float* __restrict__ Wk, const float* __restrict__ bk,
                    const float* __restrict__ Wv, const float* __restrict__ bv,
                    const float* __restrict__ gamma, const float* __restrict__ beta,
                    float* __restrict__ out, float* __restrict__ attn)
{
  __shared__ __align__(16) unsigned short pnl[PNL_ELEMS];   // 28672 B
  __shared__ __align__(16) unsigned short qlnS[16 * QLN_ROW]; // 9472 B
  __shared__ __align__(16) unsigned short qkcb[16 * QK_ROW];  // 28928 B (qk, then cbar)
  __shared__ float sred[16 * 4 * 8];                          // scores then probs, 2048 B

  const int tid = threadIdx.x;
  const int pos0 = blockIdx.x * kTile;
  const int lane = tid & 63;
  const int wv = tid >> 6;      // wave id 0..3
  const int l15 = lane & 15;
  const int g = lane >> 4;      // quarter-wave

  const float4* WkF4 = reinterpret_cast<const float4*>(Wk);
  const float4* WvF4 = reinterpret_cast<const float4*>(Wv);
  const float4* ctxF4 = reinterpret_cast<const float4*>(context);

  // ================= A: LayerNorm -> qln bf16 (h-blocked, k-padded) ============
  {
    const int r = tid >> 4, s = tid & 15;
    const float4* q4 = reinterpret_cast<const float4*>(query) + (size_t)(pos0 + r) * 49;
    const float4* g4 = reinterpret_cast<const float4*>(gamma);
    const float4* b4 = reinterpret_cast<const float4*>(beta);
    float4 xv[4];
    float sum = 0.f, sumsq = 0.f;
    #pragma unroll
    for (int k = 0; k < 4; ++k) {
      int i4 = s + 16 * k;
      if (i4 < 49) {
        xv[k] = q4[i4];
        sum += xv[k].x + xv[k].y + xv[k].z + xv[k].w;
        sumsq += xv[k].x*xv[k].x + xv[k].y*xv[k].y + xv[k].z*xv[k].z + xv[k].w*xv[k].w;
      }
    }
    #pragma unroll
    for (int m = 1; m < 16; m <<= 1) {
      sum += __shfl_xor(sum, m, 16);
      sumsq += __shfl_xor(sumsq, m, 16);
    }
    const float mu = sum * (1.0f / 196.0f);
    const float var = sumsq * (1.0f / 196.0f) - mu * mu;
    const float rstd = rsqrtf(var + kEps);
    #pragma unroll
    for (int k = 0; k < 4; ++k) {
      int i4 = s + 16 * k;
      if (i4 < 49) {
        float4 gv = g4[i4], bt = b4[i4];
        float vo[4];
        vo[0] = (xv[k].x - mu) * rstd * gv.x + bt.x;
        vo[1] = (xv[k].y - mu) * rstd * gv.y + bt.y;
        vo[2] = (xv[k].z - mu) * rstd * gv.z + bt.z;
        vo[3] = (xv[k].w - mu) * rstd * gv.w + bt.w;
        #pragma unroll
        for (int j = 0; j < 4; ++j) {
          int oo = 4 * i4 + j;
          int hq = oo / 49, dq = oo - 49 * hq;
          qlnS[r * QLN_ROW + hq * 72 + dq] = f2bf(vo[j]);
        }
      }
    }
    // zero k-pad (d=49..71 per h-block)
    #pragma unroll
    for (int it = 0; it < 6; ++it) {
      int pp = s + 16 * it;
      if (pp < 92) {
        int hz = pp / 23, dz = 49 + pp - 23 * hz;
        qlnS[r * QLN_ROW + hz * 72 + dz] = 0;
      }
    }
    // zero the weight panel once (pad slots stay zero across h-iterations)
    #pragma unroll
    for (int k = 0; k < 7; ++k) {
      int idx8 = tid + 256 * k;  // < 1792, covers 14336 elems
      *reinterpret_cast<int4*>(&pnl[idx8 * 8]) = make_int4(0, 0, 0, 0);
    }
  }
  __syncthreads();

  // ================= B: GEMM1 qk = qln @ Wk (per head, MFMA) ====================
  for (int h = 0; h < 4; ++h) {
    // stage Wk_h into fragment-native panel: elem B[k=d][n=c] at
    // slot ((nt*2+ks)*512 + lane*8 + i), lane = g*16 + (c&15), k = ks*32+g*8+i
    for (int it = 0; it < 10; ++it) {
      int idx = tid + 256 * it;
      if (idx < 2401) {
        int d = idx / 49, c4 = idx - 49 * d;
        float4 w = WkF4[(size_t)(h * 49 + d) * 49 + c4];
        int ks = d >> 5, gg = (d & 31) >> 3, ii = d & 7;
        float wa[4] = {w.x, w.y, w.z, w.w};
        #pragma unroll
        for (int j = 0; j < 4; ++j) {
          int cc = 4 * c4 + j;
          int nt = cc >> 4, lc = cc & 15;
          pnl[((nt << 1) | ks) * 512 + (gg * 16 + lc) * 8 + ii] = f2bf(wa[j]);
        }
      }
    }
    __syncthreads();
    {
      // A frags: lane holds A[row=l15][k=ks*32+g*8+i]
      const bf16x8 a0 = *reinterpret_cast<const bf16x8*>(&qlnS[l15 * QLN_ROW + h * 72 + g * 8]);
      const bf16x8 a1 = *reinterpret_cast<const bf16x8*>(&qlnS[l15 * QLN_ROW + h * 72 + 32 + g * 8]);
      for (int nt = wv; nt < 13; nt += 4) {
        f32x4 acc = {0.f, 0.f, 0.f, 0.f};
        bf16x8 b0 = *reinterpret_cast<const bf16x8*>(&pnl[(nt * 2 + 0) * 512 + lane * 8]);
        acc = __builtin_amdgcn_mfma_f32_16x16x32_bf16(a0, b0, acc, 0, 0, 0);
        bf16x8 b1 = *reinterpret_cast<const bf16x8*>(&pnl[(nt * 2 + 1) * 512 + lane * 8]);
        acc = __builtin_amdgcn_mfma_f32_16x16x32_bf16(a1, b1, acc, 0, 0, 0);
        // D[row=(g*4+r)][col=nt*16+l15] -> qk bf16
        #pragma unroll
        for (int r = 0; r < 4; ++r)
          qkcb[(g * 4 + r) * QK_ROW + h * 224 + nt * 16 + l15] = f2bf(acc[r]);
      }
    }
    __syncthreads();
  }

  // ================= C: scores (ctx read #1) + softmax ==========================
  const int t = tid >> 4;
  const int x = tid & 15;
  for (int n = 0; n < 8; ++n) {
    float sph[4] = {0.f, 0.f, 0.f, 0.f};
    #pragma unroll
    for (int jj = 0; jj < 4; ++jj) {
      int c4 = x + 16 * jj;
      if (c4 < 49) {
        float4 cv = ctxF4[((size_t)(pos0 + t) * 8 + n) * 49 + c4];
        #pragma unroll
        for (int hh = 0; hh < 4; ++hh) {
          int2 q = *reinterpret_cast<const int2*>(&qkcb[t * QK_ROW + hh * 224 + 4 * c4]);
          float q0 = __builtin_bit_cast(float, (unsigned)q.x << 16);
          float q1 = __builtin_bit_cast(float, (unsigned)q.x & 0xffff0000u);
          float q2 = __builtin_bit_cast(float, (unsigned)q.y << 16);
          float q3 = __builtin_bit_cast(float, (unsigned)q.y & 0xffff0000u);
          sph[hh] += q0 * cv.x + q1 * cv.y + q2 * cv.z + q3 * cv.w;
        }
      }
    }
    #pragma unroll
    for (int hh = 0; hh < 4; ++hh) {
      #pragma unroll
      for (int m = 1; m < 16; m <<= 1) sph[hh] += __shfl_xor(sph[hh], m, 16);
    }
    if (x == 0) {
      #pragma unroll
      for (int hh = 0; hh < 4; ++hh) sred[(t * 4 + hh) * 8 + n] = sph[hh];
    }
  }
  __syncthreads();
  if (tid < 64) {
    const int tt = tid & 15, hh = tid >> 4;
    float qb = 0.f;
    for (int d = 0; d < 49; ++d)
      qb += bf2f(qlnS[tt * QLN_ROW + hh * 72 + d]) * bk[hh * 49 + d];
    const int pos = pos0 + tt;
    const int bb = pos >> 14, ll = pos & (kL - 1);
    float sc[8], m = -1e30f;
    #pragma unroll
    for (int n = 0; n < 8; ++n) {
      sc[n] = (sred[(tt * 4 + hh) * 8 + n] + qb) * kScale;
      m = fmaxf(m, sc[n]);
    }
    float ssum = 0.f;
    #pragma unroll
    for (int n = 0; n < 8; ++n) { sc[n] = __expf(sc[n] - m); ssum += sc[n]; }
    const float inv = 1.0f / ssum;
    float* ap = attn + (((size_t)bb * 4 + hh) * kL + ll) * 8;
    #pragma unroll
    for (int n = 0; n < 8; ++n) {
      float p = sc[n] * inv;
      sred[(tt * 4 + hh) * 8 + n] = p;  // in-place: scores -> probs
      ap[n] = p;
    }
  }
  __syncthreads();

  // ================= D: cbar (ctx read #2) -> bf16 into qkcb ====================
  {
    float preg[4][8];
    #pragma unroll
    for (int hh = 0; hh < 4; ++hh)
      #pragma unroll
      for (int n = 0; n < 8; ++n) preg[hh][n] = sred[(t * 4 + hh) * 8 + n];
    #pragma unroll 1
    for (int jj = 0; jj < 4; ++jj) {
      int c4 = x + 16 * jj;
      if (c4 < 49) {
        float acc[4][4];
        #pragma unroll
        for (int hh = 0; hh < 4; ++hh)
          #pragma unroll
          for (int e = 0; e < 4; ++e) acc[hh][e] = 0.f;
        #pragma unroll
        for (int n = 0; n < 8; ++n) {
          float4 cv = ctxF4[((size_t)(pos0 + t) * 8 + n) * 49 + c4];
          #pragma unroll
          for (int hh = 0; hh < 4; ++hh) {
            float p = preg[hh][n];
            acc[hh][0] += p * cv.x; acc[hh][1] += p * cv.y;
            acc[hh][2] += p * cv.z; acc[hh][3] += p * cv.w;
          }
        }
        #pragma unroll
        for (int hh = 0; hh < 4; ++hh) {
          ushort4 pk;
          pk.x = f2bf(acc[hh][0]); pk.y = f2bf(acc[hh][1]);
          pk.z = f2bf(acc[hh][2]); pk.w = f2bf(acc[hh][3]);
          *reinterpret_cast<ushort4*>(&qkcb[t * QK_ROW + hh * 224 + 4 * c4]) = pk;
        }
      }
    }
    // zero c-pad 196..223 (c4p 49..55) so GEMM2 K=224 is clean
    #pragma unroll
    for (int it = 0; it < 2; ++it) {
      int ii = tid + 256 * it;
      if (ii < 448) {
        int tz = ii / 28, rem = ii - 28 * tz;
        int hz = rem / 7, c4p = 49 + rem - 7 * hz;
        ushort4 z = {0, 0, 0, 0};
        *reinterpret_cast<ushort4*>(&qkcb[tz * QK_ROW + hz * 224 + 4 * c4p]) = z;
      }
    }
    // re-zero panel for WvT layout (different pad slots than Wk panel)
    #pragma unroll
    for (int k = 0; k < 7; ++k) {
      int idx8 = tid + 256 * k;
      *reinterpret_cast<int4*>(&pnl[idx8 * 8]) = make_int4(0, 0, 0, 0);
    }
  }
  __syncthreads();

  // ================= E: GEMM2 out = cbar @ Wv^T (per head, MFMA) ================
  for (int h = 0; h < 4; ++h) {
    // stage WvT_h: B[k=c][n=o]; per float4 of Wv row o: 4 consecutive i -> b64 write
    for (int it = 0; it < 10; ++it) {
      int idx = tid + 256 * it;
      if (idx < 2401) {
        int o = idx / 49, c4 = idx - 49 * o;
        float4 w = WvF4[(size_t)(h * 49 + o) * 49 + c4];
        int c0 = 4 * c4;
        int nt = o >> 4, lo = o & 15;
        int ks = c0 >> 5, gg = (c0 & 31) >> 3, i0 = c0 & 7;
        ushort4 pk;
        pk.x = f2bf(w.x); pk.y = f2bf(w.y); pk.z = f2bf(w.z); pk.w = f2bf(w.w);
        *reinterpret_cast<ushort4*>(&pnl[(nt * 7 + ks) * 512 + (gg * 16 + lo) * 8 + i0]) = pk;
      }
    }
    __syncthreads();
    {
      f32x4 acc = {0.f, 0.f, 0.f, 0.f};
      #pragma unroll
      for (int ks = 0; ks < 7; ++ks) {
        bf16x8 a = *reinterpret_cast<const bf16x8*>(&qkcb[l15 * QK_ROW + h * 224 + ks * 32 + g * 8]);
        bf16x8 b = *reinterpret_cast<const bf16x8*>(&pnl[(wv * 7 + ks) * 512 + lane * 8]);
        acc = __builtin_amdgcn_mfma_f32_16x16x32_bf16(a, b, acc, 0, 0, 0);
      }
      int o = wv * 16 + l15;
      if (o < 49) {
        float bvv = bv[h * 49 + o];
        #pragma unroll
        for (int r = 0; r < 4; ++r) {
          int tt2 = g * 4 + r;
          out[(size_t)(pos0 + tt2) * 196 + h * 49 + o] = acc[r] + bvv;
        }
      }
    }
    __syncthreads();
  }
}
} // namespace

extern "C" void kernel_launch(void* const* d_in, const int* in_sizes, int n_in,
                              void* d_out, int out_size, void* d_ws, size_t ws_size,
                              hipStream_t stream) {
  const float* query   = (const float*)d_in[0];
  const float* context = (const float*)d_in[1];
  const float* Wk      = (const float*)d_in[2];
  const float* bk      = (const float*)d_in[3];
  const float* Wv      = (const float*)d_in[4];
  const float* bv      = (const float*)d_in[5];
  const float* gamma   = (const float*)d_in[6];
  const float* beta    = (const float*)d_in[7];
  float* outp = (float*)d_out;
  float* attn = outp + (size_t)2 * kL * 196;  // out [B,L,C] then attn_prob [B,H,L,Nv]

  const int nwg = (2 * kL) / kTile;  // 2048
  fused_triplane<<<dim3(nwg), dim3(256), 0, stream>>>(
      query, context, Wk, bk, Wv, bv, gamma, beta, outp, attn);
}